// Round 1
// baseline (1666.121 us; speedup 1.0000x reference)
//
#include <hip/hip_runtime.h>

// out = (B @ x_src) @ W, computed in-place in d_out:
//   phase 1: d_out[r,:] += v * x_src[c,:]  for each nnz (r,c,v)   (atomicAdd)
//   phase 2: d_out[r,:] = d_out[r,:] @ W    (in-place, rows staged in LDS)

#define WAVES_PER_BLOCK 4
#define RPB 32  // rows per block in the in-place GEMM

__global__ __launch_bounds__(256) void scatter_kernel(
    const float* __restrict__ x_src,
    const float* __restrict__ b_vals,
    const int* __restrict__ b_rows,
    const int* __restrict__ b_cols,
    float* __restrict__ out,
    int nnz)
{
    int wave = blockIdx.x * WAVES_PER_BLOCK + (threadIdx.x >> 6);
    int lane = threadIdx.x & 63;
    if (wave >= nnz) return;

    int r = b_rows[wave];
    int c = b_cols[wave];
    float v = b_vals[wave];

    // 64 lanes x float4 = 256 floats = one full channel row
    const float4* src = reinterpret_cast<const float4*>(x_src + (size_t)c * 256);
    float4 s = src[lane];

    float* dst = out + (size_t)r * 256 + lane * 4;
    atomicAdd(dst + 0, v * s.x);
    atomicAdd(dst + 1, v * s.y);
    atomicAdd(dst + 2, v * s.z);
    atomicAdd(dst + 3, v * s.w);
}

__global__ __launch_bounds__(256) void rowgemm_inplace_kernel(
    float* __restrict__ out,
    const float* __restrict__ W,
    int M)
{
    __shared__ float rows[RPB][256];
    int r0 = blockIdx.x * RPB;
    int tid = threadIdx.x;           // tid = output column
    int nr = min(RPB, M - r0);

    // stage this block's rows into LDS (coalesced reads)
    for (int i = 0; i < nr; i++)
        rows[i][tid] = out[(size_t)(r0 + i) * 256 + tid];
    __syncthreads();

    float acc[RPB];
#pragma unroll
    for (int i = 0; i < RPB; i++) acc[i] = 0.0f;

    for (int k = 0; k < 256; k += 4) {
        float w0 = W[(size_t)(k + 0) * 256 + tid];  // coalesced
        float w1 = W[(size_t)(k + 1) * 256 + tid];
        float w2 = W[(size_t)(k + 2) * 256 + tid];
        float w3 = W[(size_t)(k + 3) * 256 + tid];
#pragma unroll
        for (int i = 0; i < RPB; i++) {
            // wave-uniform LDS address -> broadcast, conflict-free; 16B read
            float4 rv = *reinterpret_cast<const float4*>(&rows[i][k]);
            acc[i] += rv.x * w0;
            acc[i] += rv.y * w1;
            acc[i] += rv.z * w2;
            acc[i] += rv.w * w3;
        }
    }

    for (int i = 0; i < nr; i++)
        out[(size_t)(r0 + i) * 256 + tid] = acc[i];
}

extern "C" void kernel_launch(void* const* d_in, const int* in_sizes, int n_in,
                              void* d_out, int out_size, void* d_ws, size_t ws_size,
                              hipStream_t stream) {
    const float* x_src  = (const float*)d_in[0];
    const float* W      = (const float*)d_in[1];
    const float* b_vals = (const float*)d_in[2];
    const int*   b_rows = (const int*)d_in[3];
    const int*   b_cols = (const int*)d_in[4];
    // d_in[5] is M on device; derive host-side M from out_size instead.

    const int C = 256;
    const int M = out_size / C;
    const int nnz = in_sizes[2];

    hipMemsetAsync(d_out, 0, (size_t)out_size * sizeof(float), stream);

    float* out = (float*)d_out;

    int nblk_scatter = (nnz + WAVES_PER_BLOCK - 1) / WAVES_PER_BLOCK;
    scatter_kernel<<<nblk_scatter, 256, 0, stream>>>(x_src, b_vals, b_rows, b_cols, out, nnz);

    int nblk_gemm = (M + RPB - 1) / RPB;
    rowgemm_inplace_kernel<<<nblk_gemm, 256, 0, stream>>>(out, W, M);
}

// Round 2
// 410.956 us; speedup vs baseline: 4.0543x; 4.0543x over previous
//
#include <hip/hip_runtime.h>

// out = (B @ x_src) @ W
// Phase 1 (CSR build + gather, no big atomics):
//   hist:  cnt[r]++ per nnz
//   scan:  off = exclusive_scan(cnt); cursor = off
//   fill:  pos = cursor[r]++; csr_col[pos]=c; csr_val[pos]=v
//   gather: one wave per row r: acc = sum_j v_j * x_src[c_j]; out[r] = acc
// Phase 2: out = out @ W in-place, 32 rows/block, 8row x 4col register tile/thread.

#define SCAN_BLOCK 1024
#define RPB 32

__global__ __launch_bounds__(256) void hist_kernel(
    const int* __restrict__ b_rows, int* __restrict__ cnt, int nnz)
{
    int i = blockIdx.x * 256 + threadIdx.x;
    if (i < nnz) atomicAdd(&cnt[b_rows[i]], 1);
}

__global__ __launch_bounds__(SCAN_BLOCK) void scan_kernel(
    const int* __restrict__ cnt, int* __restrict__ off,
    int* __restrict__ cursor, int M)
{
    __shared__ int wsum[SCAN_BLOCK / 64];
    __shared__ int chunk_carry;
    int tid = threadIdx.x, lane = tid & 63, wid = tid >> 6;
    if (tid == 0) chunk_carry = 0;
    __syncthreads();

    for (int base = 0; base < M; base += SCAN_BLOCK) {
        int i = base + tid;
        int v = (i < M) ? cnt[i] : 0;
        // inclusive wave scan
        int x = v;
        #pragma unroll
        for (int d = 1; d < 64; d <<= 1) {
            int y = __shfl_up(x, d);
            if (lane >= d) x += y;
        }
        if (lane == 63) wsum[wid] = x;
        __syncthreads();
        if (wid == 0) {
            int ws = (lane < SCAN_BLOCK / 64) ? wsum[lane] : 0;
            #pragma unroll
            for (int d = 1; d < SCAN_BLOCK / 64; d <<= 1) {
                int y = __shfl_up(ws, d);
                if (lane >= d) ws += y;
            }
            if (lane < SCAN_BLOCK / 64) wsum[lane] = ws;
        }
        __syncthreads();
        int wave_off = (wid > 0) ? wsum[wid - 1] : 0;
        int incl = x + wave_off + chunk_carry;   // inclusive prefix incl. carry
        int excl = incl - v;
        if (i < M) { off[i] = excl; cursor[i] = excl; }
        __syncthreads();                          // everyone done reading carry
        if (tid == SCAN_BLOCK - 1) chunk_carry = incl;
        __syncthreads();
    }
    if (tid == 0) off[M] = chunk_carry;           // == nnz
}

__global__ __launch_bounds__(256) void fill_kernel(
    const float* __restrict__ b_vals, const int* __restrict__ b_rows,
    const int* __restrict__ b_cols, int* __restrict__ cursor,
    int* __restrict__ csr_col, float* __restrict__ csr_val, int nnz)
{
    int i = blockIdx.x * 256 + threadIdx.x;
    if (i < nnz) {
        int r = b_rows[i];
        int pos = atomicAdd(&cursor[r], 1);
        csr_col[pos] = b_cols[i];
        csr_val[pos] = b_vals[i];
    }
}

__global__ __launch_bounds__(256) void gather_kernel(
    const float* __restrict__ x_src, const float* __restrict__ csr_val,
    const int* __restrict__ csr_col, const int* __restrict__ off,
    float* __restrict__ out, int M)
{
    int wave = blockIdx.x * 4 + (threadIdx.x >> 6);
    int lane = threadIdx.x & 63;
    if (wave >= M) return;

    int s = off[wave], e = off[wave + 1];
    float4 acc = make_float4(0.f, 0.f, 0.f, 0.f);
    const float4* x4 = reinterpret_cast<const float4*>(x_src);
    for (int j = s; j < e; j++) {
        int c = csr_col[j];
        float v = csr_val[j];
        float4 xs = x4[(size_t)c * 64 + lane];
        acc.x += v * xs.x; acc.y += v * xs.y;
        acc.z += v * xs.z; acc.w += v * xs.w;
    }
    reinterpret_cast<float4*>(out)[(size_t)wave * 64 + lane] = acc;
}

__global__ __launch_bounds__(256) void rowgemm2_kernel(
    float* __restrict__ out, const float* __restrict__ W, int M)
{
    __shared__ float rows[RPB][256];
    int r0 = blockIdx.x * RPB;
    int tid = threadIdx.x;

    for (int i = 0; i < RPB; i++) {
        int r = r0 + i;
        if (r < M) rows[i][tid] = out[(size_t)r * 256 + tid];
    }
    __syncthreads();

    int cg = (tid & 63) * 4;   // column base (0..252)
    int rg = tid >> 6;         // row group 0..3 -> rows rg*8..rg*8+7

    float acc[8][4];
    #pragma unroll
    for (int i = 0; i < 8; i++)
        #pragma unroll
        for (int c = 0; c < 4; c++) acc[i][c] = 0.f;

    for (int k4 = 0; k4 < 256; k4 += 4) {
        float4 w0 = *reinterpret_cast<const float4*>(&W[(size_t)(k4 + 0) * 256 + cg]);
        float4 w1 = *reinterpret_cast<const float4*>(&W[(size_t)(k4 + 1) * 256 + cg]);
        float4 w2 = *reinterpret_cast<const float4*>(&W[(size_t)(k4 + 2) * 256 + cg]);
        float4 w3 = *reinterpret_cast<const float4*>(&W[(size_t)(k4 + 3) * 256 + cg]);
        #pragma unroll
        for (int i = 0; i < 8; i++) {
            float4 rv = *reinterpret_cast<const float4*>(&rows[rg * 8 + i][k4]); // broadcast
            acc[i][0] += rv.x * w0.x; acc[i][1] += rv.x * w0.y;
            acc[i][2] += rv.x * w0.z; acc[i][3] += rv.x * w0.w;
            acc[i][0] += rv.y * w1.x; acc[i][1] += rv.y * w1.y;
            acc[i][2] += rv.y * w1.z; acc[i][3] += rv.y * w1.w;
            acc[i][0] += rv.z * w2.x; acc[i][1] += rv.z * w2.y;
            acc[i][2] += rv.z * w2.z; acc[i][3] += rv.z * w2.w;
            acc[i][0] += rv.w * w3.x; acc[i][1] += rv.w * w3.y;
            acc[i][2] += rv.w * w3.z; acc[i][3] += rv.w * w3.w;
        }
    }

    #pragma unroll
    for (int i = 0; i < 8; i++) {
        int r = r0 + rg * 8 + i;
        if (r < M) {
            float4 o = make_float4(acc[i][0], acc[i][1], acc[i][2], acc[i][3]);
            *reinterpret_cast<float4*>(&out[(size_t)r * 256 + cg]) = o;
        }
    }
}

extern "C" void kernel_launch(void* const* d_in, const int* in_sizes, int n_in,
                              void* d_out, int out_size, void* d_ws, size_t ws_size,
                              hipStream_t stream) {
    const float* x_src  = (const float*)d_in[0];
    const float* W      = (const float*)d_in[1];
    const float* b_vals = (const float*)d_in[2];
    const int*   b_rows = (const int*)d_in[3];
    const int*   b_cols = (const int*)d_in[4];

    const int C = 256;
    const int M = out_size / C;
    const int nnz = in_sizes[2];

    // workspace layout
    char* ws = (char*)d_ws;
    int*   cnt     = (int*)ws;                          ws += (size_t)M * 4;
    int*   off     = (int*)ws;                          ws += (size_t)(M + 1) * 4;
    int*   cursor  = (int*)ws;                          ws += (size_t)M * 4;
    int*   csr_col = (int*)ws;                          ws += (size_t)nnz * 4;
    float* csr_val = (float*)ws;                        ws += (size_t)nnz * 4;

    float* out = (float*)d_out;

    hipMemsetAsync(cnt, 0, (size_t)M * 4, stream);

    int nblk_nnz = (nnz + 255) / 256;
    hist_kernel<<<nblk_nnz, 256, 0, stream>>>(b_rows, cnt, nnz);
    scan_kernel<<<1, SCAN_BLOCK, 0, stream>>>(cnt, off, cursor, M);
    fill_kernel<<<nblk_nnz, 256, 0, stream>>>(b_vals, b_rows, b_cols, cursor,
                                              csr_col, csr_val, nnz);

    int nblk_gather = (M + 3) / 4;
    gather_kernel<<<nblk_gather, 256, 0, stream>>>(x_src, csr_val, csr_col, off, out, M);

    int nblk_gemm = (M + RPB - 1) / RPB;
    rowgemm2_kernel<<<nblk_gemm, 256, 0, stream>>>(out, W, M);
}

// Round 3
// 236.436 us; speedup vs baseline: 7.0468x; 1.7381x over previous
//
#include <hip/hip_runtime.h>

// out = (B @ x_src) @ W  with bf16 MFMA, fused gather+GEMM.
// Pipeline:
//   wtrans:     Wt_bf16[n][k] = bf16(W[k][n])            (128 KB, once per launch)
//   hist:       cnt[r]++ per nnz
//   scan x3:    off = exclusive_scan(cnt), cursor = off  (multi-block)
//   fill:       CSR (csr_col, csr_val) via cursor atomics
//   fused:      per block: gather 64 rows of (B@x) -> LDS bf16 (swizzled),
//               then 8 K-steps of mfma_f32_16x16x32_bf16 vs Wt, write out fp32.

typedef short bf16x8 __attribute__((ext_vector_type(8)));
typedef float f32x4  __attribute__((ext_vector_type(4)));

#define BM 64

static __device__ __forceinline__ unsigned short f2bf(float f) {
    union { float f; unsigned u; } a; a.f = f;
    unsigned r = a.u + 0x7FFFu + ((a.u >> 16) & 1u);   // RNE
    return (unsigned short)(r >> 16);
}

__global__ __launch_bounds__(256) void wtrans_kernel(
    const float* __restrict__ W, unsigned short* __restrict__ Wt)
{
    int k = blockIdx.x;            // 0..255, reads row k of W coalesced
    int n = threadIdx.x;           // 0..255
    Wt[(size_t)n * 256 + k] = f2bf(W[(size_t)k * 256 + n]);
}

__global__ __launch_bounds__(256) void hist_kernel(
    const int* __restrict__ b_rows, int* __restrict__ cnt, int nnz)
{
    int i = blockIdx.x * 256 + threadIdx.x;
    if (i < nnz) atomicAdd(&cnt[b_rows[i]], 1);
}

__global__ __launch_bounds__(1024) void scan_part_kernel(
    const int* __restrict__ cnt, int* __restrict__ partials, int M)
{
    int tid = threadIdx.x;
    int base = blockIdx.x * 4096;
    int s = 0;
    #pragma unroll
    for (int k = 0; k < 4; ++k) {
        int i = base + k * 1024 + tid;
        if (i < M) s += cnt[i];
    }
    #pragma unroll
    for (int d = 1; d < 64; d <<= 1) s += __shfl_xor(s, d);
    __shared__ int wsum[16];
    int lane = tid & 63, wid = tid >> 6;
    if (lane == 0) wsum[wid] = s;
    __syncthreads();
    if (tid == 0) {
        int t = 0;
        #pragma unroll
        for (int w = 0; w < 16; ++w) t += wsum[w];
        partials[blockIdx.x] = t;
    }
}

__global__ __launch_bounds__(64) void scan_mid_kernel(
    int* __restrict__ partials, int* __restrict__ off, int np, int M)
{
    int lane = threadIdx.x;
    int v = (lane < np) ? partials[lane] : 0;
    int x = v;
    #pragma unroll
    for (int d = 1; d < 64; d <<= 1) { int y = __shfl_up(x, d); if (lane >= d) x += y; }
    if (lane < np) partials[lane] = x - v;     // exclusive
    if (lane == 63) off[M] = x;                // total == nnz
}

__global__ __launch_bounds__(1024) void scan_apply_kernel(
    const int* __restrict__ cnt, const int* __restrict__ partials,
    int* __restrict__ off, int* __restrict__ cursor, int M)
{
    int tid = threadIdx.x;
    int base = blockIdx.x * 4096 + tid * 4;
    int4 v = make_int4(0, 0, 0, 0);
    if (base + 3 < M) v = *reinterpret_cast<const int4*>(cnt + base);
    else {
        if (base + 0 < M) v.x = cnt[base + 0];
        if (base + 1 < M) v.y = cnt[base + 1];
        if (base + 2 < M) v.z = cnt[base + 2];
    }
    int s1 = v.x + v.y, s2 = s1 + v.z, tsum = s2 + v.w;
    int x = tsum;
    int lane = tid & 63, wid = tid >> 6;
    #pragma unroll
    for (int d = 1; d < 64; d <<= 1) { int y = __shfl_up(x, d); if (lane >= d) x += y; }
    __shared__ int wsum[16];
    if (lane == 63) wsum[wid] = x;
    __syncthreads();
    if (wid == 0 && lane < 16) {
        int w = wsum[lane];
        int xx = w;
        #pragma unroll
        for (int d = 1; d < 16; d <<= 1) { int y = __shfl_up(xx, d); if (lane >= d) xx += y; }
        wsum[lane] = xx - w;  // exclusive wave offset
    }
    __syncthreads();
    int excl = (x - tsum) + wsum[wid] + partials[blockIdx.x];
    int o0 = excl, o1 = excl + v.x, o2 = excl + s1, o3 = excl + s2;
    if (base + 0 < M) { off[base + 0] = o0; cursor[base + 0] = o0; }
    if (base + 1 < M) { off[base + 1] = o1; cursor[base + 1] = o1; }
    if (base + 2 < M) { off[base + 2] = o2; cursor[base + 2] = o2; }
    if (base + 3 < M) { off[base + 3] = o3; cursor[base + 3] = o3; }
}

__global__ __launch_bounds__(256) void fill_kernel(
    const float* __restrict__ b_vals, const int* __restrict__ b_rows,
    const int* __restrict__ b_cols, int* __restrict__ cursor,
    int* __restrict__ csr_col, float* __restrict__ csr_val, int nnz)
{
    int i = blockIdx.x * 256 + threadIdx.x;
    if (i < nnz) {
        int r = b_rows[i];
        int pos = atomicAdd(&cursor[r], 1);
        csr_col[pos] = b_cols[i];
        csr_val[pos] = b_vals[i];
    }
}

// Fused: gather rows into LDS (bf16, XOR-swizzled) then MFMA vs Wt.
__global__ __launch_bounds__(256) void fused_kernel(
    const float* __restrict__ x_src, const float* __restrict__ csr_val,
    const int* __restrict__ csr_col, const int* __restrict__ off,
    const unsigned short* __restrict__ Wt, float* __restrict__ out, int M)
{
    __shared__ __align__(16) unsigned char Alds[BM * 512];  // [row][k] bf16, swizzled

    int lane = threadIdx.x & 63;
    int wid  = threadIdx.x >> 6;
    int r0   = blockIdx.x * BM;

    // ---- gather phase: wave w gathers rows 16w..16w+15, lane covers cols 4*lane..4*lane+3
    const float4* x4 = reinterpret_cast<const float4*>(x_src);
    for (int i = 0; i < 16; ++i) {
        int row = wid * 16 + i;
        int r = r0 + row;
        float4 acc = make_float4(0.f, 0.f, 0.f, 0.f);
        if (r < M) {
            int s = off[r], e = off[r + 1];
            for (int j = s; j < e; ++j) {
                int c = csr_col[j];
                float v = csr_val[j];
                float4 xs = x4[(size_t)c * 64 + lane];
                acc.x += v * xs.x; acc.y += v * xs.y;
                acc.z += v * xs.z; acc.w += v * xs.w;
            }
        }
        ushort4 h;
        h.x = f2bf(acc.x); h.y = f2bf(acc.y); h.z = f2bf(acc.z); h.w = f2bf(acc.w);
        int byte = row * 512 + lane * 8;
        byte ^= (row & 7) << 4;                 // bank-conflict swizzle
        *reinterpret_cast<ushort4*>(Alds + byte) = h;
    }
    __syncthreads();

    // ---- MFMA phase: wave w computes all 64 rows x cols [64w, 64w+64)
    f32x4 acc[4][4] = {};                        // [m_tile][n_tile]
    const char* wt = reinterpret_cast<const char*>(Wt);  // [n][k] bf16: byte = n*512 + k*2
    int nbase = wid * 64;
    int arow15 = lane & 15;
    int kgrp   = (lane >> 4) * 16;               // byte offset of lane's 8-bf16 k-run

    for (int s = 0; s < 8; ++s) {
        bf16x8 a[4], b[4];
        #pragma unroll
        for (int m = 0; m < 4; ++m) {
            int row = m * 16 + arow15;
            int byte = row * 512 + s * 64 + kgrp;
            byte ^= (row & 7) << 4;
            a[m] = *reinterpret_cast<const bf16x8*>(Alds + byte);
        }
        #pragma unroll
        for (int t = 0; t < 4; ++t) {
            int n = nbase + t * 16 + arow15;
            b[t] = *reinterpret_cast<const bf16x8*>(wt + (size_t)n * 512 + s * 64 + kgrp);
        }
        #pragma unroll
        for (int m = 0; m < 4; ++m)
            #pragma unroll
            for (int t = 0; t < 4; ++t)
                acc[m][t] = __builtin_amdgcn_mfma_f32_16x16x32_bf16(a[m], b[t], acc[m][t], 0, 0, 0);
    }

    // ---- epilogue: D row = m*16 + 4*(lane>>4) + reg, col = nbase + t*16 + (lane&15)
    #pragma unroll
    for (int m = 0; m < 4; ++m) {
        int rowb = r0 + m * 16 + (lane >> 4) * 4;
        #pragma unroll
        for (int r = 0; r < 4; ++r) {
            if (rowb + r < M) {
                #pragma unroll
                for (int t = 0; t < 4; ++t)
                    out[(size_t)(rowb + r) * 256 + nbase + t * 16 + arow15] = acc[m][t][r];
            }
        }
    }
}

extern "C" void kernel_launch(void* const* d_in, const int* in_sizes, int n_in,
                              void* d_out, int out_size, void* d_ws, size_t ws_size,
                              hipStream_t stream) {
    const float* x_src  = (const float*)d_in[0];
    const float* W      = (const float*)d_in[1];
    const float* b_vals = (const float*)d_in[2];
    const int*   b_rows = (const int*)d_in[3];
    const int*   b_cols = (const int*)d_in[4];

    const int C = 256;
    const int M = out_size / C;
    const int nnz = in_sizes[2];

    // workspace layout (Wt first: needs 16B alignment)
    char* ws = (char*)d_ws;
    unsigned short* Wt = (unsigned short*)ws;           ws += 256 * 256 * 2;     // 128 KB
    int*   cnt     = (int*)ws;                          ws += (size_t)M * 4;
    int*   off     = (int*)ws;                          ws += (size_t)(M + 1) * 4;
    int*   cursor  = (int*)ws;                          ws += (size_t)M * 4;
    int*   partials= (int*)ws;                          ws += 64 * 4;
    int*   csr_col = (int*)ws;                          ws += (size_t)nnz * 4;
    float* csr_val = (float*)ws;                        ws += (size_t)nnz * 4;

    float* out = (float*)d_out;

    hipMemsetAsync(cnt, 0, (size_t)M * 4, stream);

    wtrans_kernel<<<256, 256, 0, stream>>>(W, Wt);

    int nblk_nnz = (nnz + 255) / 256;
    hist_kernel<<<nblk_nnz, 256, 0, stream>>>(b_rows, cnt, nnz);

    int nb = (M + 4095) / 4096;
    scan_part_kernel<<<nb, 1024, 0, stream>>>(cnt, partials, M);
    scan_mid_kernel<<<1, 64, 0, stream>>>(partials, off, nb, M);
    scan_apply_kernel<<<nb, 1024, 0, stream>>>(cnt, partials, off, cursor, M);

    fill_kernel<<<nblk_nnz, 256, 0, stream>>>(b_vals, b_rows, b_cols, cursor,
                                              csr_col, csr_val, nnz);

    int nblk_fused = (M + BM - 1) / BM;
    fused_kernel<<<nblk_fused, 256, 0, stream>>>(x_src, csr_val, csr_col, off,
                                                 Wt, out, M);
}